// Round 8
// baseline (221.611 us; speedup 1.0000x reference)
//
#include <hip/hip_runtime.h>
#include <cstdint>
#include <cstddef>

typedef unsigned int u32;
typedef unsigned long long u64;

#define NB 8192
#define BIMG 2
#define WPR (NB / 64)   // 128 u64 words per mask row

// ---------------- workspace layout (bytes) ----------------
#define WS_KCOUNT 0
#define WS_KEYS   256
#define WS_BOXES  (WS_KEYS + BIMG * NB * 8)          // 131328
#define WS_PROB   (WS_BOXES + BIMG * NB * 16)        // 393472
#define WS_SBOXES (WS_PROB + BIMG * NB * 4)          // 459008
#define WS_SPROB  (WS_SBOXES + BIMG * NB * 16)       // 721152
#define WS_REMV   (WS_SPROB + BIMG * NB * 4)         // 786688 (unused in fast path)
#define WS_MASK   (WS_REMV + BIMG * WPR * 8 + 256)   // 788992 (pad)
#define WS_ROWNZ  (WS_MASK + (size_t)BIMG * NB * WPR * 8)
#define WS_NEEDED (WS_ROWNZ + (size_t)BIMG * NB)     // ~17.6 MB

// ---------------------------------------------------------------------------
// Kernel 1: sigmoid + box decode + sort-key build (NO atomics)
// ---------------------------------------------------------------------------
__global__ void decode_kernel(const float* __restrict__ offsets,
                              const float* __restrict__ labels,
                              const float* __restrict__ anchors,
                              u64* __restrict__ keys,
                              float4* __restrict__ boxes,
                              float* __restrict__ prob) {
  int idx = blockIdx.x * blockDim.x + threadIdx.x;
  if (idx >= BIMG * NB) return;
  int n = idx & (NB - 1);

  float logit = labels[idx];
  float p = 1.0f / (1.0f + expf(-logit));
  bool valid = p > 0.5f;

  const float4 an = ((const float4*)anchors)[n];   // x1,y1,x2,y2
  float acx = (an.x + an.z) / 2.0f;
  float acy = (an.y + an.w) / 2.0f;
  float aw = an.z - an.x;
  float ah = an.w - an.y;

  const float4 of = ((const float4*)offsets)[idx]; // gcx,gcy,gw,gh
  float cx = of.x * aw / 10.0f + acx;
  float cy = of.y * ah / 10.0f + acy;
  float w = expf(of.z / 5.0f) * aw;
  float h = expf(of.w / 5.0f) * ah;

  float4 bx;
  bx.x = cx - w / 2.0f;
  bx.y = cy - h / 2.0f;
  bx.z = cx + w / 2.0f;
  bx.w = cy + h / 2.0f;
  boxes[idx] = bx;
  prob[idx] = p;

  u32 e = valid ? (__float_as_uint(p) ^ 0x80000000u) : 0u;
  keys[idx] = ((u64)e << 32) | (u32)(~(u32)n);
}

// ---------------------------------------------------------------------------
// Kernel 2: per-image bitonic sort (desc) + valid count + fused sorted gather
// ---------------------------------------------------------------------------
__global__ __launch_bounds__(1024) void sort_kernel(u64* __restrict__ keys,
                                                    const float4* __restrict__ boxes,
                                                    const float* __restrict__ prob,
                                                    float4* __restrict__ sboxes,
                                                    float* __restrict__ sprob,
                                                    u32* __restrict__ kcount) {
  __shared__ u64 s[NB];                 // 64 KB
  __shared__ u32 scnt;
  const int b = blockIdx.x;
  u64* kb = keys + (size_t)b * NB;
  if (threadIdx.x == 0) scnt = 0;
  u32 lc = 0;
  for (int i = threadIdx.x; i < NB; i += 1024) {
    u64 k = kb[i];
    s[i] = k;
    lc += ((u32)(k >> 32) != 0u) ? 1u : 0u;
  }
  // wave reduction of local valid count
  for (int off = 32; off > 0; off >>= 1) lc += __shfl_down(lc, off, 64);
  __syncthreads();                       // scnt init + s[] loaded
  if ((threadIdx.x & 63) == 0) atomicAdd(&scnt, lc);   // 16 LDS atomics
  __syncthreads();
  if (threadIdx.x == 0) kcount[b] = scnt;

  for (int k = 2; k <= NB; k <<= 1) {
    for (int j = k >> 1; j > 0; j >>= 1) {
      for (int p = threadIdx.x; p < NB / 2; p += 1024) {
        int i = ((p & ~(j - 1)) << 1) | (p & (j - 1));
        int ixj = i | j;
        u64 a = s[i];
        u64 c = s[ixj];
        bool desc = (i & k) == 0;
        if ((a < c) == desc) { s[i] = c; s[ixj] = a; }
      }
      __syncthreads();
    }
  }

  // write back keys + fused gather into sorted order
  const float4* bx = boxes + (size_t)b * NB;
  const float* pb = prob + (size_t)b * NB;
  for (int i = threadIdx.x; i < NB; i += 1024) {
    u64 k = s[i];
    kb[i] = k;
    u32 oi = (u32)(~k);                 // original anchor index
    sboxes[(size_t)b * NB + i] = bx[oi];
    sprob[(size_t)b * NB + i]  = pb[oi];
  }
}

// ---------------------------------------------------------------------------
// Kernel 4: overlap bitmask build + per-row nonzero flag.
// mask[b][i][w] bit l = (j=64w+l) > i && j < K && IoU(i,j) > 0.5
// ---------------------------------------------------------------------------
__global__ __launch_bounds__(256) void mask_kernel(const float4* __restrict__ sboxes,
                                                   const u32* __restrict__ kcount,
                                                   u64* __restrict__ mask,
                                                   unsigned char* __restrict__ rownz) {
  const int i = blockIdx.x;       // sorted row
  const int b = blockIdx.y;
  const int K = (int)kcount[b];
  if (i >= K) return;
  const int wave = threadIdx.x >> 6;
  const int lane = threadIdx.x & 63;
  __shared__ u32 anyf[4];
  const float4* sb = sboxes + (size_t)b * NB;
  const float4 bi = sb[i];
  const float area_i = (bi.z - bi.x) * (bi.w - bi.y);
  u64* mrow = mask + ((size_t)b * NB + i) * WPR;
  bool any = false;
  for (int pass = 0; pass < WPR / 4; ++pass) {
    int w = pass * 4 + wave;
    u64 word = 0;
    if ((w + 1) * 64 > i && w * 64 < K) {   // uniform per wave
      int j = w * 64 + lane;
      float4 bj = sb[j];
      float lx = fmaxf(bi.x, bj.x);
      float ly = fmaxf(bi.y, bj.y);
      float rx = fminf(bi.z, bj.z);
      float ry = fminf(bi.w, bj.w);
      float iw = fmaxf(rx - lx, 0.0f);
      float ih = fmaxf(ry - ly, 0.0f);
      float inter = iw * ih;
      float area_j = (bj.z - bj.x) * (bj.w - bj.y);
      float iou = inter / (area_i + area_j - inter);
      bool pred = (j > i) && (j < K) && (iou > 0.5f);
      word = __ballot(pred);
      any = any || (word != 0ull);
    }
    if (lane == 0) mrow[w] = word;
  }
  if (lane == 0) anyf[wave] = any ? 1u : 0u;
  __syncthreads();
  if (threadIdx.x == 0) {
    u32 a = anyf[0] | anyf[1] | anyf[2] | anyf[3];
    rownz[(size_t)b * NB + i] = (unsigned char)(a ? 1 : 0);
  }
}

// ---------------------------------------------------------------------------
// Kernel 5: chunked greedy scan + fused output. 8 waves / image.
// Row loads are SPECULATIVE on rownz (addresses independent of ku), issued in
// phase 1 so their RTT drains at barrier A concurrently with wave 0's serial
// resolve. Phase 2 is register/LDS-only: mask by ku, post word t+1 slot.
// Posts select strictly-future words, so stale words < t in accumulators are
// never observed (same invariant as prior rounds).
// ---------------------------------------------------------------------------
#define SCAN_WAVES 8
#define MAXROWS 10                 // 10-bit nz-window per row wave covers 64 bits

__device__ inline u64 rdl64(u64 v, int lane) {
  u32 lo = (u32)__builtin_amdgcn_readlane((int)(u32)v, lane);
  u32 hi = (u32)__builtin_amdgcn_readlane((int)(u32)(v >> 32), lane);
  return ((u64)hi << 32) | lo;
}

__device__ inline u64 shflxor64(u64 v, int off) {
  u32 lo = (u32)v, hi = (u32)(v >> 32);
  lo = (u32)__shfl_xor((int)lo, off, 64);
  hi = (u32)__shfl_xor((int)hi, off, 64);
  return ((u64)hi << 32) | lo;
}

__global__ __launch_bounds__(512) void scan_kernel(const u64* __restrict__ mask,
                                                   const unsigned char* __restrict__ rownz,
                                                   const u32* __restrict__ kcount,
                                                   const float4* __restrict__ sboxes,
                                                   const float* __restrict__ sprob,
                                                   float* __restrict__ out) {
  __shared__ u64 s_remv[WPR];            // finalized rc words (1 KB)
  __shared__ u64 s_slot[2][SCAN_WAVES];  // double-buffered per-wave word-(t+1)
  __shared__ u64 s_ku;
  __shared__ u64 s_nzw;                  // nzword(t) published one stage early
  const int b = blockIdx.x;
  const int tid = threadIdx.x;
  const int w = tid >> 6;                // wave id 0..7
  const int l = tid & 63;
  const int K = (int)kcount[b];
  const u64* mb = mask + (size_t)b * NB * WPR;
  const unsigned char* nzb = rownz + (size_t)b * NB;
  const int NC = min(WPR, (K + 63) >> 6);

  if (tid < 2 * SCAN_WAVES) ((u64*)s_slot)[tid] = 0;

  // per-wave accumulators: lane l owns words l (plo) and l+64 (phi)
  u64 plo = 0, phi = 0;
  // row-wave in-stage load state (persist across the two phases of a stage)
  u64 Llo[MAXROWS], Lhi[MAXROWS], bq[MAXROWS];
  // wave-0 pipeline regs
  u64 dw = 0;
  unsigned char nzc = 0;

  if (w == 0) {
    if (NC > 0) {
      dw = (l < K) ? mb[(size_t)l * WPR] : 0ull;
      nzc = nzb[l];
    }
    u64 nzw0 = __ballot(nzc != 0);
    if (l == 0) s_nzw = nzw0;
  }
  __syncthreads();

  for (int t = 0; t < NC; ++t) {
    // ---------------- phase 1 ----------------
    if (w == 0) {
      // prefetch next chunk's diagonal + rownz (drains at barrier A)
      u64 dwn = 0;
      unsigned char nznb = 0;
      if (t + 1 < NC) {
        int i = (t + 1) * 64 + l;
        dwn = (i < K) ? mb[(size_t)i * WPR + (t + 1)] : 0ull;
        nznb = nzb[i];
      }
      // merge word t from slots (posted at stage t-1, buffer (t+1)&1)
      u64 val = s_slot[(t + 1) & 1][l & (SCAN_WAVES - 1)];
#pragma unroll
      for (int off = 1; off < SCAN_WAVES; off <<= 1) val |= shflxor64(val, off);
      int lo = t * 64;
      u64 tail = (lo + 64 <= K) ? 0ull : ((~0ull) << (K - lo));
      u64 rc = val | tail;
      u64 nzword = __ballot(nzc != 0);
      // serial within-chunk resolve, pruned by current rc
      u64 nzd = __ballot(dw != 0ull) & ~rc;
      while (nzd) {
        int tt = __builtin_ctzll(nzd);
        rc |= rdl64(dw, tt);
        nzd &= ~(1ull << tt) & ~rc;
      }
      u64 ku = (~rc) & nzword;
      if (l == 0) { s_ku = ku; s_remv[t] = rc; }
      dw = dwn;       // rotate pipeline
      nzc = nznb;
    } else {
      // speculative row loads from the nz-window (addresses independent of ku)
      u64 nzw = s_nzw;
      u64 kk = (nzw >> ((w - 1) * MAXROWS)) & ((1ull << MAXROWS) - 1ull);
#pragma unroll
      for (int q = 0; q < MAXROWS; ++q) {
        bool has = (kk != 0ull);
        int tq = has ? __builtin_ctzll(kk) : 0;
        if (has) kk &= kk - 1;
        bq[q] = has ? (1ull << ((w - 1) * MAXROWS + tq)) : 0ull;
        Llo[q] = 0; Lhi[q] = 0;
        if (has) {
          const u64* rp = mb + (size_t)(t * 64 + (w - 1) * MAXROWS + tq) * WPR;
          Llo[q] = rp[l];
          Lhi[q] = rp[64 + l];
        }
      }
    }
    __syncthreads();                     // barrier A: rc/ku published, loads drained

    // ---------------- phase 2 (register/LDS only) ----------------
    if (w == 0) {
      u64 nzw_next = __ballot(nzc != 0); // nzc now = rownz(t+1)
      if (l == 0) s_nzw = nzw_next;
    } else {
      u64 ku = s_ku;
#pragma unroll
      for (int q = 0; q < MAXROWS; ++q) {
        if (ku & bq[q]) { plo |= Llo[q]; phi |= Lhi[q]; }
      }
      int wsel = t + 1;
      u64 v = (wsel < 64) ? plo : phi;
      if (l == (wsel & 63)) s_slot[t & 1][w] = v;
    }
    __syncthreads();                     // barrier B: slots/nzw settled
  }

  // ---------------- fused output ----------------
  const float4* sbx = sboxes + (size_t)b * NB;
  const float* spb = sprob + (size_t)b * NB;
  for (int p = tid; p < NB; p += 512) {
    bool kp = false;
    if (p < K) {
      u64 wv = s_remv[p >> 6];
      kp = !((wv >> (p & 63)) & 1ull);
    }
    float4 bv = sbx[p];
    if (!kp) { bv.x = 0.0f; bv.y = 0.0f; bv.z = 0.0f; bv.w = 0.0f; }
    ((float4*)out)[(size_t)b * NB + p] = bv;
    out[(size_t)BIMG * NB * 4 + (size_t)b * NB + p] = kp ? spb[p] : 0.0f;
    out[(size_t)BIMG * NB * 5 + (size_t)b * NB + p] = kp ? 1.0f : 0.0f;
  }
}

// ---------------------------------------------------------------------------
// Fallback NMS kernel (used only if workspace is too small)
// ---------------------------------------------------------------------------
__global__ __launch_bounds__(1024) void nms_kernel(const u64* __restrict__ keys,
                                                   const float4* __restrict__ boxes,
                                                   const float* __restrict__ prob,
                                                   const u32* __restrict__ kcount,
                                                   float* __restrict__ out) {
  __shared__ float4 sb[NB];
  __shared__ unsigned char flag[NB];
  const int b = blockIdx.x;
  const int t = threadIdx.x;
  const u64* kb = keys + (size_t)b * NB;
  const float4* bx = boxes + (size_t)b * NB;
  const int K = (int)kcount[b];

  for (int p = t; p < NB; p += 1024) {
    u32 idx = (u32)(~kb[p]);
    sb[p] = bx[idx];
    flag[p] = (p < K) ? (unsigned char)0 : (unsigned char)1;
  }
  __syncthreads();

  for (int i = 0; i < K; ++i) {
    if (flag[i]) continue;
    float4 bi = sb[i];
    float area_i = (bi.z - bi.x) * (bi.w - bi.y);
    for (int j = i + 1 + t; j < K; j += 1024) {
      float4 bj = sb[j];
      float lx = fmaxf(bi.x, bj.x);
      float ly = fmaxf(bi.y, bj.y);
      float rx = fminf(bi.z, bj.z);
      float ry = fminf(bi.w, bj.w);
      float iw = fmaxf(rx - lx, 0.0f);
      float ih = fmaxf(ry - ly, 0.0f);
      float inter = iw * ih;
      float area_j = (bj.z - bj.x) * (bj.w - bj.y);
      float iou = inter / (area_i + area_j - inter);
      if (iou > 0.5f) flag[j] = (unsigned char)1;
    }
    __syncthreads();
  }

  float4* oboxes = (float4*)(out) + (size_t)b * NB;
  float* oscores = out + (size_t)BIMG * NB * 4 + (size_t)b * NB;
  float* okeep   = out + (size_t)BIMG * NB * 5 + (size_t)b * NB;
  const float* pb = prob + (size_t)b * NB;
  for (int p = t; p < NB; p += 1024) {
    bool kp = (p < K) && (flag[p] == 0);
    float4 bv = sb[p];
    if (!kp) { bv.x = 0.0f; bv.y = 0.0f; bv.z = 0.0f; bv.w = 0.0f; }
    oboxes[p] = bv;
    u32 idx = (u32)(~kb[p]);
    oscores[p] = kp ? pb[idx] : 0.0f;
    okeep[p] = kp ? 1.0f : 0.0f;
  }
}

// ---------------------------------------------------------------------------
extern "C" void kernel_launch(void* const* d_in, const int* in_sizes, int n_in,
                              void* d_out, int out_size, void* d_ws, size_t ws_size,
                              hipStream_t stream) {
  const float* offsets = (const float*)d_in[0];   // [B,N,4] f32
  const float* labels  = (const float*)d_in[1];   // [B,N,1] f32
  const float* anchors = (const float*)d_in[2];   // [N,4]   f32
  float* out = (float*)d_out;

  char* ws = (char*)d_ws;
  u32*    kcount = (u32*)(ws + WS_KCOUNT);
  u64*    keys   = (u64*)(ws + WS_KEYS);
  float4* boxes  = (float4*)(ws + WS_BOXES);
  float*  prob   = (float*)(ws + WS_PROB);
  float4* sboxes = (float4*)(ws + WS_SBOXES);
  float*  sprob  = (float*)(ws + WS_SPROB);

  int total = BIMG * NB;
  decode_kernel<<<(total + 255) / 256, 256, 0, stream>>>(
      offsets, labels, anchors, keys, boxes, prob);

  sort_kernel<<<BIMG, 1024, 0, stream>>>(keys, boxes, prob, sboxes, sprob, kcount);

  if (ws_size >= WS_NEEDED) {
    u64*    mask   = (u64*)(ws + WS_MASK);
    unsigned char* rownz = (unsigned char*)(ws + WS_ROWNZ);

    mask_kernel<<<dim3(NB, BIMG), 256, 0, stream>>>(sboxes, kcount, mask, rownz);

    scan_kernel<<<BIMG, 512, 0, stream>>>(mask, rownz, kcount, sboxes, sprob, out);
  } else {
    nms_kernel<<<BIMG, 1024, 0, stream>>>(keys, boxes, prob, kcount, out);
  }
}